// Round 13
// baseline (384.828 us; speedup 1.0000x reference)
//
#include <hip/hip_runtime.h>
#include <hip/hip_bf16.h>

#define D_MODEL 192
#define D_INNER 384
#define DT_RANK 12
#define BATCH   4
#define HH      128
#define WW      128
#define LL      (HH*WW)   // 16384 = 2^14

typedef __hip_bfloat16 bf16;
typedef __attribute__((ext_vector_type(8))) short short8;
typedef __attribute__((ext_vector_type(4))) float f32x4;

__device__ __forceinline__ float b2f(bf16 v) { return __bfloat162float(v); }
__device__ __forceinline__ bf16  f2b(float v) { return __float2bfloat16(v); }
__device__ __forceinline__ unsigned short fbits(float v) {
    union { bf16 h; unsigned short u; } c; c.h = __float2bfloat16(v); return c.u;
}
__device__ __forceinline__ float bits2f(unsigned short u) {
    union { unsigned u32; float f; } c; c.u32 = (unsigned)u << 16; return c.f;
}
// hardware transcendentals (v_exp_f32 / v_log_f32 / v_rcp_f32, ~1ulp)
__device__ __forceinline__ float fsig(float x) {
    return __builtin_amdgcn_rcpf(1.f + __expf(-x));
}
__device__ __forceinline__ float fsoftplus(float s) {
    return (s > 20.f) ? s : __logf(1.f + __expf(s));
}

// ---------------- K0: f32 -> bf16 convert (n multiple of 2048) -------------
__global__ __launch_bounds__(256) void k_cvt(const float* __restrict__ src,
                                             unsigned short* __restrict__ dst) {
    size_t i = ((size_t)blockIdx.x * 256 + threadIdx.x) * 8;
    float4 f0 = *(const float4*)(src + i);
    float4 f1 = *(const float4*)(src + i + 4);
    unsigned short u[8] = {fbits(f0.x), fbits(f0.y), fbits(f0.z), fbits(f0.w),
                           fbits(f1.x), fbits(f1.y), fbits(f1.z), fbits(f1.w)};
    *(int4*)(dst + i) = *(const int4*)u;
}

// ---------------- K0b: dt_w (384x12 f32) -> padded bf16 [384][32] ----------
__global__ __launch_bounds__(256) void k_padw(const float* __restrict__ dt_w,
                                              unsigned short* __restrict__ wp) {
    int i = blockIdx.x * 256 + threadIdx.x;    // 384*32 = 12288
    int d = i >> 5, r = i & 31;
    float v = (r < 12) ? dt_w[d * 12 + r] : 0.f;
    wp[i] = fbits(v);
}

// ---------------- K1: xz = Xb @ Winb^T (MFMA) ; split xi (NCHW) / z --------
__global__ __launch_bounds__(256) void k_gemm_xz(const unsigned short* __restrict__ Xb,
                                                 const unsigned short* __restrict__ Wb,
                                                 bf16* __restrict__ xi,
                                                 bf16* __restrict__ z) {
    __shared__ short Al[128][40];
    __shared__ short Bl[128][40];
    int t = threadIdx.x, lane = t & 63, w = t >> 6;
    int wr = w >> 1, wc = w & 1;
    int n0 = blockIdx.x * 128, m0 = blockIdx.y * 128;
    f32x4 acc[4][4];
    f32x4 zv = {0.f, 0.f, 0.f, 0.f};
    #pragma unroll
    for (int i = 0; i < 4; i++)
        #pragma unroll
        for (int j = 0; j < 4; j++) acc[i][j] = zv;

    int sr = t >> 1, sc = (t & 1) * 16;
    const unsigned short* Ab = Xb + (size_t)(m0 + sr) * D_MODEL + sc;
    const unsigned short* Bb = Wb + (size_t)(n0 + sr) * D_MODEL + sc;

    for (int k0 = 0; k0 < D_MODEL; k0 += 32) {
        int4 av0 = *(const int4*)(Ab + k0);
        int4 av1 = *(const int4*)(Ab + k0 + 8);
        int4 bv0 = *(const int4*)(Bb + k0);
        int4 bv1 = *(const int4*)(Bb + k0 + 8);
        __syncthreads();
        *(int4*)&Al[sr][sc]     = av0;
        *(int4*)&Al[sr][sc + 8] = av1;
        *(int4*)&Bl[sr][sc]     = bv0;
        *(int4*)&Bl[sr][sc + 8] = bv1;
        __syncthreads();
        short8 af[4], bfr[4];
        #pragma unroll
        for (int f = 0; f < 4; f++) {
            af[f]  = *(const short8*)&Al[wr * 64 + f * 16 + (lane & 15)][(lane >> 4) * 8];
            bfr[f] = *(const short8*)&Bl[wc * 64 + f * 16 + (lane & 15)][(lane >> 4) * 8];
        }
        #pragma unroll
        for (int i = 0; i < 4; i++)
            #pragma unroll
            for (int j = 0; j < 4; j++)
                acc[i][j] = __builtin_amdgcn_mfma_f32_16x16x32_bf16(af[i], bfr[j], acc[i][j], 0, 0, 0);
    }

    #pragma unroll
    for (int i = 0; i < 4; i++) {
        int mB = m0 + wr * 64 + i * 16 + ((lane >> 4) << 2);
        int lb = mB >> 14, l = mB & (LL - 1);
        #pragma unroll
        for (int j = 0; j < 4; j++) {
            int n = n0 + wc * 64 + j * 16 + (lane & 15);
            f32x4 v = acc[i][j];
            if (n < D_INNER) {
                union { short4 s4; unsigned short u[4]; } p;
                #pragma unroll
                for (int r = 0; r < 4; r++) p.u[r] = fbits(v[r]);
                *(short4*)&xi[((size_t)lb * D_INNER + n) * LL + l] = p.s4;
            } else {
                #pragma unroll
                for (int r = 0; r < 4; r++)
                    z[(size_t)(mB + r) * D_INNER + (n - D_INNER)] = f2b(v[r]);
            }
        }
    }
}

// ---------------- K2: depthwise 3x3 conv (zero pad) + bias + SiLU ----------
__global__ __launch_bounds__(256) void k_conv_silu(const bf16* __restrict__ xi,
                                                   const float* __restrict__ w,
                                                   const float* __restrict__ bias,
                                                   bf16* __restrict__ xs) {
    __shared__ float rb[18][132];
    int bid = blockIdx.x;
    int dl = bid >> 3;              // chunk-local (lb*384+d)
    int d  = dl % D_INNER;
    int y0 = (bid & 7) * 16;
    int t  = threadIdx.x;
    const bf16* src = xi + (size_t)dl * LL;

    for (int rr = (t >> 4); rr < 18; rr += 16) {
        int c  = t & 15;
        int yy = y0 + rr - 1;
        float vals[8];
        if (yy >= 0 && yy < HH) {
            short8 s8 = *(const short8*)&src[yy * WW + c * 8];
            #pragma unroll
            for (int j = 0; j < 8; j++) vals[j] = bits2f((unsigned short)s8[j]);
        } else {
            #pragma unroll
            for (int j = 0; j < 8; j++) vals[j] = 0.f;
        }
        #pragma unroll
        for (int j = 0; j < 8; j++) rb[rr][1 + c * 8 + j] = vals[j];
        if (c == 0)  rb[rr][0]   = 0.f;
        if (c == 15) rb[rr][129] = 0.f;
    }
    float wk[9];
    #pragma unroll
    for (int k = 0; k < 9; k++) wk[k] = w[d * 9 + k];
    float bs = bias[d];
    __syncthreads();

    int x = t & 127, half = t >> 7;
    #pragma unroll
    for (int i = 0; i < 8; i++) {
        int R = half * 8 + i;
        float acc = bs;
        #pragma unroll
        for (int dy = 0; dy < 3; dy++)
            #pragma unroll
            for (int dx = 0; dx < 3; dx++)
                acc += rb[R + dy][x + dx] * wk[dy * 3 + dx];
        float s = acc * fsig(acc);
        xs[(size_t)dl * LL + (y0 + R) * WW + x] = f2b(s);
    }
}

// ---------------- K3: x_dbl: dts -> bf16 [l][32] padded; Bs,Cs dense f32 ---
// 8-deep load batching: 8 independent strided loads in flight per chunk
__global__ __launch_bounds__(256) void k_xdbl(const bf16* __restrict__ xs,
                                              const float* __restrict__ xpw,
                                              unsigned short* __restrict__ dtsb,
                                              float* __restrict__ bsd,
                                              float* __restrict__ csd) {
    int t   = threadIdx.x;
    int bid = blockIdx.x;
    int lb  = bid >> 6;
    int l   = ((bid & 63) << 8) + t;
    float acc[14] = {};
    const bf16* base = xs + (size_t)lb * D_INNER * LL + l;
    for (int d0 = 0; d0 < D_INNER; d0 += 8) {
        float v[8];
        #pragma unroll
        for (int q = 0; q < 8; q++) v[q] = b2f(base[(size_t)(d0 + q) * LL]);
        #pragma unroll
        for (int q = 0; q < 8; q++) {
            #pragma unroll
            for (int k = 0; k < 14; k++) acc[k] += xpw[k * D_INNER + d0 + q] * v[q];
        }
    }
    unsigned short pk[32];
    #pragma unroll
    for (int k = 0; k < 12; k++) pk[k] = fbits(acc[k]);
    #pragma unroll
    for (int k = 12; k < 32; k++) pk[k] = 0;
    int4* dst = (int4*)&dtsb[((size_t)lb * LL + l) << 5];
    #pragma unroll
    for (int q = 0; q < 4; q++) dst[q] = ((const int4*)pk)[q];
    bsd[(size_t)lb * LL + l] = acc[12];
    csd[(size_t)lb * LL + l] = acc[13];
}

// ---------------- K3b: delta = softplus(dt_w @ dts + dt_b)  (MFMA) ---------
__global__ __launch_bounds__(256) void k_delta(const unsigned short* __restrict__ wp,
                                               const unsigned short* __restrict__ dtsb,
                                               const float* __restrict__ dt_b,
                                               bf16* __restrict__ delta) {
    __shared__ float bsm[16];
    int m0 = blockIdx.x * 16;
    int nbk = blockIdx.y;
    int lb = nbk >> 5;                 // 32 n-tiles (512 wide) per batch
    int n0 = (nbk & 31) * 512;
    int t = threadIdx.x, lane = t & 63, w = t >> 6;
    if (t < 16) bsm[t] = dt_b[m0 + t];
    short8 af = *(const short8*)&wp[(m0 + (lane & 15)) * 32 + (lane >> 4) * 8];
    __syncthreads();
    f32x4 zv = {0.f, 0.f, 0.f, 0.f};
    int row = (lane >> 4) * 4;
    #pragma unroll
    for (int s = 0; s < 8; s++) {
        int n = n0 + w * 128 + s * 16 + (lane & 15);
        short8 bf8 = *(const short8*)&dtsb[(((size_t)lb * LL + n) << 5) + (lane >> 4) * 8];
        f32x4 c = __builtin_amdgcn_mfma_f32_16x16x32_bf16(af, bf8, zv, 0, 0, 0);
        #pragma unroll
        for (int r = 0; r < 4; r++) {
            float sv = c[r] + bsm[row + r];
            float dl = fsoftplus(sv);
            delta[((size_t)lb * D_INNER + m0 + row + r) * LL + n] = f2b(dl);
        }
    }
}

// ---------------- K4: block-parallel scan, one 512-thread block per seq ----
__global__ __launch_bounds__(512, 4) void k_scan(const bf16* __restrict__ xs,
                                                 const bf16* __restrict__ delta,
                                                 const float* __restrict__ bsd,
                                                 const float* __restrict__ A_logs,
                                                 bf16* __restrict__ h) {
    int seq = blockIdx.x;
    int d   = seq % D_INNER;
    int lb  = seq / D_INNER;
    int t    = threadIdx.x;
    int lane = t & 63;
    int wid  = t >> 6;

    float Aval = -__expf(A_logs[d]);

    int l0 = t * 32;
    const bf16* xv = xs + (size_t)seq * LL + l0;
    const bf16* dv = delta + (size_t)seq * LL + l0;
    const float* bsp = bsd + (size_t)lb * LL + l0;

    float xsv[32], dlv[32];
    {
        int4 raw[4], rawd[4];
        const int4* src = (const int4*)xv;
        const int4* srcd = (const int4*)dv;
        #pragma unroll
        for (int q = 0; q < 4; q++) { raw[q] = src[q]; rawd[q] = srcd[q]; }
        const unsigned short* u = (const unsigned short*)raw;
        const unsigned short* ud = (const unsigned short*)rawd;
        #pragma unroll
        for (int j = 0; j < 32; j++) { xsv[j] = bits2f(u[j]); dlv[j] = bits2f(ud[j]); }
    }

    float a[32], bb[32];
    float Ar = 1.f, Br = 0.f;
    #pragma unroll
    for (int j = 0; j < 32; j++) {
        float Bsv = bsp[j];
        float dl = dlv[j];
        float av = __expf(dl * Aval);
        float bv = dl * Bsv * xsv[j];
        a[j] = av; bb[j] = bv;
        Br = av * Br + bv;
        Ar *= av;
    }

    #pragma unroll
    for (int off = 1; off < 64; off <<= 1) {
        float Ap = __shfl_up(Ar, off);
        float Bp = __shfl_up(Br, off);
        if (lane >= off) { Br = Ar * Bp + Br; Ar *= Ap; }
    }

    __shared__ float LA[8], LB[8];
    if (lane == 63) { LA[wid] = Ar; LB[wid] = Br; }
    __syncthreads();
    float Bwp = 0.f;
    for (int ww = 0; ww < wid; ww++) { Bwp = LA[ww] * Bwp + LB[ww]; }

    float Ae = __shfl_up(Ar, 1), Be = __shfl_up(Br, 1);
    if (lane == 0) { Ae = 1.f; Be = 0.f; }
    float hcur = Ae * Bwp + Be;

    unsigned pk[16];
    unsigned lo = 0;
    #pragma unroll
    for (int j = 0; j < 32; j++) {
        hcur = a[j] * hcur + bb[j];
        unsigned bits = fbits(hcur);
        if (j & 1) pk[j >> 1] = lo | (bits << 16);
        else       lo = bits;
    }
    int4* dst = (int4*)(h + (size_t)seq * LL + l0);
    #pragma unroll
    for (int q = 0; q < 4; q++) dst[q] = ((int4*)pk)[q];
}

// ---------------- K5: 3 dilated replicate-pad depthwise convs + combine ----
__global__ __launch_bounds__(256) void k_mconv(const bf16* __restrict__ h,
                                               const float* __restrict__ k1w,
                                               const float* __restrict__ k2w,
                                               const float* __restrict__ k3w,
                                               const float* __restrict__ alpha,
                                               bf16* __restrict__ hf) {
    __shared__ float rb[26][144];
    int bid = blockIdx.x;
    int dl = bid >> 3;
    int d  = dl % D_INNER;
    int y0 = (bid & 7) * 16;
    int t  = threadIdx.x;
    const bf16* src = h + (size_t)dl * LL;

    for (int rr = (t >> 4); rr < 26; rr += 16) {
        int c  = t & 15;
        int yy = min(max(y0 + rr - 5, 0), HH - 1);
        short8 s8 = *(const short8*)&src[yy * WW + c * 8];
        float vals[8];
        #pragma unroll
        for (int j = 0; j < 8; j++) vals[j] = bits2f((unsigned short)s8[j]);
        #pragma unroll
        for (int j = 0; j < 8; j++) rb[rr][5 + c * 8 + j] = vals[j];
        if (c == 0) {
            #pragma unroll
            for (int q = 0; q < 5; q++) rb[rr][q] = vals[0];
        }
        if (c == 15) {
            #pragma unroll
            for (int q = 0; q < 5; q++) rb[rr][133 + q] = vals[7];
        }
    }
    float w1[9], w2[9], w3[9];
    #pragma unroll
    for (int k = 0; k < 9; k++) {
        w1[k] = k1w[d * 9 + k];
        w2[k] = k2w[d * 9 + k];
        w3[k] = k3w[d * 9 + k];
    }
    float a0 = alpha[0], a1 = alpha[1], a2 = alpha[2];
    __syncthreads();

    int x = t & 127, half = t >> 7;
    #pragma unroll
    for (int i = 0; i < 8; i++) {
        int R = half * 8 + i;
        float s1 = 0.f, s2 = 0.f, s3 = 0.f;
        #pragma unroll
        for (int dy = 0; dy < 3; dy++)
            #pragma unroll
            for (int dx = 0; dx < 3; dx++) {
                int k = dy * 3 + dx;
                s1 += rb[R + 5 + (dy - 1)]    [5 + x + (dx - 1)]     * w1[k];
                s2 += rb[R + 5 + 3 * (dy - 1)][5 + x + 3 * (dx - 1)] * w2[k];
                s3 += rb[R + 5 + 5 * (dy - 1)][5 + x + 5 * (dx - 1)] * w3[k];
            }
        hf[(size_t)dl * LL + (y0 + R) * WW + x] = f2b(a0 * s1 + a1 * s2 + a2 * s3);
    }
}

// ---------------- K6: LDS-transpose LN: y=hf*Cs+xs*Ds; LN(d); *silu(z) -----
__global__ __launch_bounds__(256) void k_ln(const bf16* __restrict__ hf,
                                            const bf16* __restrict__ xs,
                                            const float* __restrict__ csd,
                                            const float* __restrict__ Ds,
                                            const float* __restrict__ ln_g,
                                            const float* __restrict__ ln_b,
                                            const bf16* __restrict__ z,
                                            bf16* __restrict__ yout) {
    __shared__ float vt[384][36];
    __shared__ float csh[32], mu[32], rs[32];
    __shared__ float gsh[384], bsh[384], dsh[384];
    __shared__ float sred[8][33], qred[8][33];

    int bid = blockIdx.x;
    int lb = bid >> 9;                 // LL/32 = 512 tiles per batch
    int l0 = (bid & 511) * 32;
    int t = threadIdx.x;

    if (t < 32) csh[t] = csd[(size_t)lb * LL + l0 + t];
    for (int i = t; i < 384; i += 256) {
        gsh[i] = ln_g[i]; bsh[i] = ln_b[i]; dsh[i] = Ds[i];
    }
    __syncthreads();

    #pragma unroll
    for (int p = 0; p < 6; p++) {
        int d = p * 64 + (t >> 2);
        int loff = (t & 3) * 8;
        size_t off = ((size_t)lb * D_INNER + d) * LL + l0 + loff;
        short8 h8 = *(const short8*)&hf[off];
        short8 x8 = *(const short8*)&xs[off];
        float dsv = dsh[d];
        float vv[8];
        #pragma unroll
        for (int j = 0; j < 8; j++)
            vv[j] = bits2f((unsigned short)h8[j]) * csh[loff + j]
                  + bits2f((unsigned short)x8[j]) * dsv;
        *(float4*)&vt[d][loff]     = *(float4*)&vv[0];
        *(float4*)&vt[d][loff + 4] = *(float4*)&vv[4];
    }
    __syncthreads();

    {
        int l = t & 31, ch = t >> 5;
        float s = 0.f, q = 0.f;
        #pragma unroll 8
        for (int dd = 0; dd < 48; dd++) {
            float v = vt[ch * 48 + dd][l];
            s += v; q += v * v;
        }
        sred[ch][l] = s; qred[ch][l] = q;
    }
    __syncthreads();
    if (t < 32) {
        float s = 0.f, q = 0.f;
        #pragma unroll
        for (int c = 0; c < 8; c++) { s += sred[c][t]; q += qred[c][t]; }
        float m = s * (1.f / D_INNER);
        float var = q * (1.f / D_INNER) - m * m;
        mu[t] = m; rs[t] = rsqrtf(var + 1e-5f);
    }
    __syncthreads();

    {
        int l = t & 31, ch = t >> 5;
        int d0 = ch * 48;
        size_t row = ((size_t)lb * LL + l0 + l) * D_INNER + d0;
        const short8* zp = (const short8*)&z[row];
        short8* yp = (short8*)&yout[row];
        float m = mu[l], r = rs[l];
        #pragma unroll
        for (int c = 0; c < 6; c++) {
            short8 z8 = zp[c];
            unsigned short ub[8];
            #pragma unroll
            for (int j = 0; j < 8; j++) {
                int d = d0 + c * 8 + j;
                float v = vt[d][l];
                float yn = (v - m) * r * gsh[d] + bsh[d];
                float zv = bits2f((unsigned short)z8[j]);
                float sz = zv * fsig(zv);
                ub[j] = fbits(yn * sz);
            }
            yp[c] = *(short8*)ub;
        }
    }
}

// ---------------- K7: out = Y @ Woutb^T (MFMA, f32 output) -----------------
__global__ __launch_bounds__(256) void k_gemm_out(const bf16* __restrict__ Y,
                                                  const unsigned short* __restrict__ Wb,
                                                  float* __restrict__ out,
                                                  int b_off) {
    __shared__ short Al[128][40];
    __shared__ short Bl[64][40];
    int t = threadIdx.x, lane = t & 63, w = t >> 6;
    int wr = w >> 1, wc = w & 1;
    int n0 = blockIdx.x * 64, m0 = blockIdx.y * 128;
    f32x4 acc[4][2];
    f32x4 zv = {0.f, 0.f, 0.f, 0.f};
    #pragma unroll
    for (int i = 0; i < 4; i++) { acc[i][0] = zv; acc[i][1] = zv; }

    int sr = t >> 1, sc = (t & 1) * 16;
    const unsigned short* Ab = (const unsigned short*)Y + (size_t)(m0 + sr) * D_INNER + sc;
    int br = t >> 2, bc = (t & 3) * 8;
    const unsigned short* Bb = Wb + (size_t)(n0 + br) * D_INNER + bc;

    for (int k0 = 0; k0 < D_INNER; k0 += 32) {
        int4 av0 = *(const int4*)(Ab + k0);
        int4 av1 = *(const int4*)(Ab + k0 + 8);
        int4 bv0 = *(const int4*)(Bb + k0);
        __syncthreads();
        *(int4*)&Al[sr][sc]     = av0;
        *(int4*)&Al[sr][sc + 8] = av1;
        *(int4*)&Bl[br][bc]     = bv0;
        __syncthreads();
        short8 af[4], bfr[2];
        #pragma unroll
        for (int f = 0; f < 4; f++)
            af[f] = *(const short8*)&Al[wr * 64 + f * 16 + (lane & 15)][(lane >> 4) * 8];
        #pragma unroll
        for (int f = 0; f < 2; f++)
            bfr[f] = *(const short8*)&Bl[wc * 32 + f * 16 + (lane & 15)][(lane >> 4) * 8];
        #pragma unroll
        for (int i = 0; i < 4; i++)
            #pragma unroll
            for (int j = 0; j < 2; j++)
                acc[i][j] = __builtin_amdgcn_mfma_f32_16x16x32_bf16(af[i], bfr[j], acc[i][j], 0, 0, 0);
    }

    size_t gm = (size_t)b_off * LL + m0;
    #pragma unroll
    for (int i = 0; i < 4; i++) {
        int mB = wr * 64 + i * 16 + ((lane >> 4) << 2);
        #pragma unroll
        for (int j = 0; j < 2; j++) {
            int n = n0 + wc * 32 + j * 16 + (lane & 15);
            f32x4 v = acc[i][j];
            #pragma unroll
            for (int r = 0; r < 4; r++)
                out[(gm + mB + r) * D_MODEL + n] = v[r];
        }
    }
}

extern "C" void kernel_launch(void* const* d_in, const int* in_sizes, int n_in,
                              void* d_out, int out_size, void* d_ws, size_t ws_size,
                              hipStream_t stream) {
    const float* x        = (const float*)d_in[0];
    const float* Win      = (const float*)d_in[1];
    const float* conv_w   = (const float*)d_in[2];
    const float* conv_b   = (const float*)d_in[3];
    const float* x_proj_w = (const float*)d_in[4];
    const float* dt_w     = (const float*)d_in[5];
    const float* dt_b     = (const float*)d_in[6];
    const float* A_logs   = (const float*)d_in[7];
    const float* Ds       = (const float*)d_in[8];
    const float* k3w      = (const float*)d_in[9];
    const float* k3_1w    = (const float*)d_in[10];
    const float* k3_2w    = (const float*)d_in[11];
    const float* alpha    = (const float*)d_in[12];
    const float* ln_g     = (const float*)d_in[13];
    const float* ln_b     = (const float*)d_in[14];
    const float* Wout     = (const float*)d_in[15];

    // fixed head: bf16 copies of Win, Wout, padded dt_w
    unsigned short* Winb  = (unsigned short*)d_ws;
    unsigned short* Woutb = Winb + 2 * D_INNER * D_MODEL;      // 147456
    unsigned short* wpb   = Woutb + D_MODEL * D_INNER;         // +73728
    char* pbase = (char*)(wpb + D_INNER * 32);                 // +12288

    const size_t head = (size_t)(2 * D_INNER * D_MODEL + D_MODEL * D_INNER + D_INNER * 32) * 2;
    const size_t per_batch = (size_t)4 * D_INNER * LL * 2   // b0..b3 bf16
                           + (size_t)2 * LL * 4              // bsd + csd f32
                           + (size_t)LL * 32 * 2             // dtsb bf16
                           + (size_t)LL * D_MODEL * 2;       // Xb bf16
    int nb = (int)((ws_size - head) / per_batch);
    if (nb > BATCH) nb = BATCH;
    if (nb < 1) nb = 1;

    size_t Sb = (size_t)nb * D_INNER * LL;
    bf16* b0 = (bf16*)pbase;         // xi -> delta -> hf
    bf16* b1 = b0 + Sb;              // xs
    bf16* b2 = b1 + Sb;              // z (NHWC)
    bf16* b3 = b2 + Sb;              // h -> gated y (NHWC)
    float* bsd = (float*)(b3 + Sb);            // nb*LL
    float* csd = bsd + (size_t)nb * LL;        // nb*LL
    unsigned short* dtsb = (unsigned short*)(csd + (size_t)nb * LL);  // nb*LL*32
    unsigned short* Xb = dtsb + (size_t)nb * LL * 32;

    k_cvt <<<(2 * D_INNER * D_MODEL) / 2048, 256, 0, stream>>>(Win, Winb);
    k_cvt <<<(D_MODEL * D_INNER) / 2048, 256, 0, stream>>>(Wout, Woutb);
    k_padw<<<(D_INNER * 32) / 256, 256, 0, stream>>>(dt_w, wpb);

    for (int boff = 0; boff < BATCH; boff += nb) {
        int cur = BATCH - boff < nb ? BATCH - boff : nb;
        k_cvt     <<<(cur * LL * D_MODEL) / 2048, 256, 0, stream>>>(x + (size_t)boff * LL * D_MODEL, Xb);
        k_gemm_xz <<<dim3(6, cur * 128), 256, 0, stream>>>(Xb, Winb, b0, b2);
        k_conv_silu<<<cur * D_INNER * 8, 256, 0, stream>>>(b0, conv_w, conv_b, b1);
        k_xdbl    <<<cur * 64, 256, 0, stream>>>(b1, x_proj_w, dtsb, bsd, csd);
        k_delta   <<<dim3(24, cur * 32), 256, 0, stream>>>(wpb, dtsb, dt_b, b0);
        k_scan    <<<cur * D_INNER, 512, 0, stream>>>(b1, b0, bsd, A_logs, b3);
        k_mconv   <<<cur * D_INNER * 8, 256, 0, stream>>>(b3, k3w, k3_1w, k3_2w, alpha, b0);
        k_ln      <<<cur * 512, 256, 0, stream>>>(b0, b1, csd, Ds, ln_g, ln_b, b2, b3);
        k_gemm_out<<<dim3(3, cur * 128), 256, 0, stream>>>(b3, Woutb, (float*)d_out, boff);
    }
}

// Round 14
// 343.651 us; speedup vs baseline: 1.1198x; 1.1198x over previous
//
#include <hip/hip_runtime.h>
#include <hip/hip_bf16.h>

#define D_MODEL 192
#define D_INNER 384
#define DT_RANK 12
#define BATCH   4
#define HH      128
#define WW      128
#define LL      (HH*WW)   // 16384 = 2^14

typedef __hip_bfloat16 bf16;
typedef __attribute__((ext_vector_type(8))) short short8;
typedef __attribute__((ext_vector_type(4))) float f32x4;

__device__ __forceinline__ float b2f(bf16 v) { return __bfloat162float(v); }
__device__ __forceinline__ bf16  f2b(float v) { return __float2bfloat16(v); }
__device__ __forceinline__ unsigned short fbits(float v) {
    union { bf16 h; unsigned short u; } c; c.h = __float2bfloat16(v); return c.u;
}
__device__ __forceinline__ float bits2f(unsigned short u) {
    union { unsigned u32; float f; } c; c.u32 = (unsigned)u << 16; return c.f;
}
// hardware transcendentals (v_exp_f32 / v_log_f32 / v_rcp_f32, ~1ulp)
__device__ __forceinline__ float fsig(float x) {
    return __builtin_amdgcn_rcpf(1.f + __expf(-x));
}
__device__ __forceinline__ float fsoftplus(float s) {
    return (s > 20.f) ? s : __logf(1.f + __expf(s));
}

// ---------------- K0: f32 -> bf16 convert (n multiple of 2048) -------------
__global__ __launch_bounds__(256) void k_cvt(const float* __restrict__ src,
                                             unsigned short* __restrict__ dst) {
    size_t i = ((size_t)blockIdx.x * 256 + threadIdx.x) * 8;
    float4 f0 = *(const float4*)(src + i);
    float4 f1 = *(const float4*)(src + i + 4);
    unsigned short u[8] = {fbits(f0.x), fbits(f0.y), fbits(f0.z), fbits(f0.w),
                           fbits(f1.x), fbits(f1.y), fbits(f1.z), fbits(f1.w)};
    *(int4*)(dst + i) = *(const int4*)u;
}

// ---------------- K0b: dt_w (384x12 f32) -> padded bf16 [384][32] ----------
__global__ __launch_bounds__(256) void k_padw(const float* __restrict__ dt_w,
                                              unsigned short* __restrict__ wp) {
    int i = blockIdx.x * 256 + threadIdx.x;    // 384*32 = 12288
    int d = i >> 5, r = i & 31;
    float v = (r < 12) ? dt_w[d * 12 + r] : 0.f;
    wp[i] = fbits(v);
}

// ---------------- K1: xz = Xb @ Winb^T (MFMA) ; split xi (NCHW) / z --------
__global__ __launch_bounds__(256) void k_gemm_xz(const unsigned short* __restrict__ Xb,
                                                 const unsigned short* __restrict__ Wb,
                                                 bf16* __restrict__ xi,
                                                 bf16* __restrict__ z) {
    __shared__ short Al[128][40];
    __shared__ short Bl[128][40];
    int t = threadIdx.x, lane = t & 63, w = t >> 6;
    int wr = w >> 1, wc = w & 1;
    int n0 = blockIdx.x * 128, m0 = blockIdx.y * 128;
    f32x4 acc[4][4];
    f32x4 zv = {0.f, 0.f, 0.f, 0.f};
    #pragma unroll
    for (int i = 0; i < 4; i++)
        #pragma unroll
        for (int j = 0; j < 4; j++) acc[i][j] = zv;

    int sr = t >> 1, sc = (t & 1) * 16;
    const unsigned short* Ab = Xb + (size_t)(m0 + sr) * D_MODEL + sc;
    const unsigned short* Bb = Wb + (size_t)(n0 + sr) * D_MODEL + sc;

    for (int k0 = 0; k0 < D_MODEL; k0 += 32) {
        int4 av0 = *(const int4*)(Ab + k0);
        int4 av1 = *(const int4*)(Ab + k0 + 8);
        int4 bv0 = *(const int4*)(Bb + k0);
        int4 bv1 = *(const int4*)(Bb + k0 + 8);
        __syncthreads();
        *(int4*)&Al[sr][sc]     = av0;
        *(int4*)&Al[sr][sc + 8] = av1;
        *(int4*)&Bl[sr][sc]     = bv0;
        *(int4*)&Bl[sr][sc + 8] = bv1;
        __syncthreads();
        short8 af[4], bfr[4];
        #pragma unroll
        for (int f = 0; f < 4; f++) {
            af[f]  = *(const short8*)&Al[wr * 64 + f * 16 + (lane & 15)][(lane >> 4) * 8];
            bfr[f] = *(const short8*)&Bl[wc * 64 + f * 16 + (lane & 15)][(lane >> 4) * 8];
        }
        #pragma unroll
        for (int i = 0; i < 4; i++)
            #pragma unroll
            for (int j = 0; j < 4; j++)
                acc[i][j] = __builtin_amdgcn_mfma_f32_16x16x32_bf16(af[i], bfr[j], acc[i][j], 0, 0, 0);
    }

    #pragma unroll
    for (int i = 0; i < 4; i++) {
        int mB = m0 + wr * 64 + i * 16 + ((lane >> 4) << 2);
        int lb = mB >> 14, l = mB & (LL - 1);
        #pragma unroll
        for (int j = 0; j < 4; j++) {
            int n = n0 + wc * 64 + j * 16 + (lane & 15);
            f32x4 v = acc[i][j];
            if (n < D_INNER) {
                union { short4 s4; unsigned short u[4]; } p;
                #pragma unroll
                for (int r = 0; r < 4; r++) p.u[r] = fbits(v[r]);
                *(short4*)&xi[((size_t)lb * D_INNER + n) * LL + l] = p.s4;
            } else {
                #pragma unroll
                for (int r = 0; r < 4; r++)
                    z[(size_t)(mB + r) * D_INNER + (n - D_INNER)] = f2b(v[r]);
            }
        }
    }
}

// ---------------- K2: depthwise 3x3 conv (zero pad) + bias + SiLU ----------
__global__ __launch_bounds__(256) void k_conv_silu(const bf16* __restrict__ xi,
                                                   const float* __restrict__ w,
                                                   const float* __restrict__ bias,
                                                   bf16* __restrict__ xs) {
    __shared__ float rb[18][132];
    int bid = blockIdx.x;
    int dl = bid >> 3;              // chunk-local (lb*384+d)
    int d  = dl % D_INNER;
    int y0 = (bid & 7) * 16;
    int t  = threadIdx.x;
    const bf16* src = xi + (size_t)dl * LL;

    for (int rr = (t >> 4); rr < 18; rr += 16) {
        int c  = t & 15;
        int yy = y0 + rr - 1;
        float vals[8];
        if (yy >= 0 && yy < HH) {
            short8 s8 = *(const short8*)&src[yy * WW + c * 8];
            #pragma unroll
            for (int j = 0; j < 8; j++) vals[j] = bits2f((unsigned short)s8[j]);
        } else {
            #pragma unroll
            for (int j = 0; j < 8; j++) vals[j] = 0.f;
        }
        #pragma unroll
        for (int j = 0; j < 8; j++) rb[rr][1 + c * 8 + j] = vals[j];
        if (c == 0)  rb[rr][0]   = 0.f;
        if (c == 15) rb[rr][129] = 0.f;
    }
    float wk[9];
    #pragma unroll
    for (int k = 0; k < 9; k++) wk[k] = w[d * 9 + k];
    float bs = bias[d];
    __syncthreads();

    int x = t & 127, half = t >> 7;
    #pragma unroll
    for (int i = 0; i < 8; i++) {
        int R = half * 8 + i;
        float acc = bs;
        #pragma unroll
        for (int dy = 0; dy < 3; dy++)
            #pragma unroll
            for (int dx = 0; dx < 3; dx++)
                acc += rb[R + dy][x + dx] * wk[dy * 3 + dx];
        float s = acc * fsig(acc);
        xs[(size_t)dl * LL + (y0 + R) * WW + x] = f2b(s);
    }
}

// ---------------- K3: x_dbl: 64l x 4dg blocks, LDS-reduced -----------------
// grid cur*256; wave = one dgroup (96 d's) x 64 l; 4x TLP vs before
__global__ __launch_bounds__(256) void k_xdbl(const bf16* __restrict__ xs,
                                              const float* __restrict__ xpw,
                                              unsigned short* __restrict__ dtsb,
                                              float* __restrict__ bsd,
                                              float* __restrict__ csd) {
    __shared__ float part[4][64][17];
    int bid = blockIdx.x;
    int lb  = bid >> 8;              // 256 tiles per batch
    int l0  = (bid & 255) * 64;
    int t = threadIdx.x;
    int l = t & 63, dg = t >> 6;

    const bf16* base = xs + (size_t)lb * D_INNER * LL + l0 + l;
    float acc[14] = {};
    for (int d0 = dg * 96; d0 < dg * 96 + 96; d0 += 8) {
        float v[8];
        #pragma unroll
        for (int q = 0; q < 8; q++) v[q] = b2f(base[(size_t)(d0 + q) * LL]);
        #pragma unroll
        for (int q = 0; q < 8; q++) {
            #pragma unroll
            for (int k = 0; k < 14; k++) acc[k] += xpw[k * D_INNER + d0 + q] * v[q];
        }
    }
    #pragma unroll
    for (int k = 0; k < 14; k++) part[dg][l][k] = acc[k];
    __syncthreads();

    if (t < 64) {
        float s[14];
        #pragma unroll
        for (int k = 0; k < 14; k++)
            s[k] = part[0][t][k] + part[1][t][k] + part[2][t][k] + part[3][t][k];
        unsigned short pk[32];
        #pragma unroll
        for (int k = 0; k < 12; k++) pk[k] = fbits(s[k]);
        #pragma unroll
        for (int k = 12; k < 32; k++) pk[k] = 0;
        int4* dst = (int4*)&dtsb[((size_t)lb * LL + l0 + t) << 5];
        #pragma unroll
        for (int q = 0; q < 4; q++) dst[q] = ((const int4*)pk)[q];
        bsd[(size_t)lb * LL + l0 + t] = s[12];
        csd[(size_t)lb * LL + l0 + t] = s[13];
    }
}

// ---------------- K3b: delta = softplus(dt_w @ dts + dt_b)  (MFMA) ---------
__global__ __launch_bounds__(256) void k_delta(const unsigned short* __restrict__ wp,
                                               const unsigned short* __restrict__ dtsb,
                                               const float* __restrict__ dt_b,
                                               bf16* __restrict__ delta) {
    __shared__ float bsm[16];
    int m0 = blockIdx.x * 16;
    int nbk = blockIdx.y;
    int lb = nbk >> 5;                 // 32 n-tiles (512 wide) per batch
    int n0 = (nbk & 31) * 512;
    int t = threadIdx.x, lane = t & 63, w = t >> 6;
    if (t < 16) bsm[t] = dt_b[m0 + t];
    short8 af = *(const short8*)&wp[(m0 + (lane & 15)) * 32 + (lane >> 4) * 8];
    __syncthreads();
    f32x4 zv = {0.f, 0.f, 0.f, 0.f};
    int row = (lane >> 4) * 4;
    #pragma unroll
    for (int s = 0; s < 8; s++) {
        int n = n0 + w * 128 + s * 16 + (lane & 15);
        short8 bf8 = *(const short8*)&dtsb[(((size_t)lb * LL + n) << 5) + (lane >> 4) * 8];
        f32x4 c = __builtin_amdgcn_mfma_f32_16x16x32_bf16(af, bf8, zv, 0, 0, 0);
        #pragma unroll
        for (int r = 0; r < 4; r++) {
            float sv = c[r] + bsm[row + r];
            float dl = fsoftplus(sv);
            delta[((size_t)lb * D_INNER + m0 + row + r) * LL + n] = f2b(dl);
        }
    }
}

// ---------------- K4: block-parallel scan, one 512-thread block per seq ----
__global__ __launch_bounds__(512, 4) void k_scan(const bf16* __restrict__ xs,
                                                 const bf16* __restrict__ delta,
                                                 const float* __restrict__ bsd,
                                                 const float* __restrict__ A_logs,
                                                 bf16* __restrict__ h) {
    int seq = blockIdx.x;
    int d   = seq % D_INNER;
    int lb  = seq / D_INNER;
    int t    = threadIdx.x;
    int lane = t & 63;
    int wid  = t >> 6;

    float Aval = -__expf(A_logs[d]);

    int l0 = t * 32;
    const bf16* xv = xs + (size_t)seq * LL + l0;
    const bf16* dv = delta + (size_t)seq * LL + l0;
    const float* bsp = bsd + (size_t)lb * LL + l0;

    float xsv[32], dlv[32];
    {
        int4 raw[4], rawd[4];
        const int4* src = (const int4*)xv;
        const int4* srcd = (const int4*)dv;
        #pragma unroll
        for (int q = 0; q < 4; q++) { raw[q] = src[q]; rawd[q] = srcd[q]; }
        const unsigned short* u = (const unsigned short*)raw;
        const unsigned short* ud = (const unsigned short*)rawd;
        #pragma unroll
        for (int j = 0; j < 32; j++) { xsv[j] = bits2f(u[j]); dlv[j] = bits2f(ud[j]); }
    }

    float a[32], bb[32];
    float Ar = 1.f, Br = 0.f;
    #pragma unroll
    for (int j = 0; j < 32; j++) {
        float Bsv = bsp[j];
        float dl = dlv[j];
        float av = __expf(dl * Aval);
        float bv = dl * Bsv * xsv[j];
        a[j] = av; bb[j] = bv;
        Br = av * Br + bv;
        Ar *= av;
    }

    #pragma unroll
    for (int off = 1; off < 64; off <<= 1) {
        float Ap = __shfl_up(Ar, off);
        float Bp = __shfl_up(Br, off);
        if (lane >= off) { Br = Ar * Bp + Br; Ar *= Ap; }
    }

    __shared__ float LA[8], LB[8];
    if (lane == 63) { LA[wid] = Ar; LB[wid] = Br; }
    __syncthreads();
    float Bwp = 0.f;
    for (int ww = 0; ww < wid; ww++) { Bwp = LA[ww] * Bwp + LB[ww]; }

    float Ae = __shfl_up(Ar, 1), Be = __shfl_up(Br, 1);
    if (lane == 0) { Ae = 1.f; Be = 0.f; }
    float hcur = Ae * Bwp + Be;

    unsigned pk[16];
    unsigned lo = 0;
    #pragma unroll
    for (int j = 0; j < 32; j++) {
        hcur = a[j] * hcur + bb[j];
        unsigned bits = fbits(hcur);
        if (j & 1) pk[j >> 1] = lo | (bits << 16);
        else       lo = bits;
    }
    int4* dst = (int4*)(h + (size_t)seq * LL + l0);
    #pragma unroll
    for (int q = 0; q < 4; q++) dst[q] = ((int4*)pk)[q];
}

// ---------------- K5: 3 dilated replicate-pad depthwise convs + combine ----
__global__ __launch_bounds__(256) void k_mconv(const bf16* __restrict__ h,
                                               const float* __restrict__ k1w,
                                               const float* __restrict__ k2w,
                                               const float* __restrict__ k3w,
                                               const float* __restrict__ alpha,
                                               bf16* __restrict__ hf) {
    __shared__ float rb[26][144];
    int bid = blockIdx.x;
    int dl = bid >> 3;
    int d  = dl % D_INNER;
    int y0 = (bid & 7) * 16;
    int t  = threadIdx.x;
    const bf16* src = h + (size_t)dl * LL;

    for (int rr = (t >> 4); rr < 26; rr += 16) {
        int c  = t & 15;
        int yy = min(max(y0 + rr - 5, 0), HH - 1);
        short8 s8 = *(const short8*)&src[yy * WW + c * 8];
        float vals[8];
        #pragma unroll
        for (int j = 0; j < 8; j++) vals[j] = bits2f((unsigned short)s8[j]);
        #pragma unroll
        for (int j = 0; j < 8; j++) rb[rr][5 + c * 8 + j] = vals[j];
        if (c == 0) {
            #pragma unroll
            for (int q = 0; q < 5; q++) rb[rr][q] = vals[0];
        }
        if (c == 15) {
            #pragma unroll
            for (int q = 0; q < 5; q++) rb[rr][133 + q] = vals[7];
        }
    }
    float w1[9], w2[9], w3[9];
    #pragma unroll
    for (int k = 0; k < 9; k++) {
        w1[k] = k1w[d * 9 + k];
        w2[k] = k2w[d * 9 + k];
        w3[k] = k3w[d * 9 + k];
    }
    float a0 = alpha[0], a1 = alpha[1], a2 = alpha[2];
    __syncthreads();

    int x = t & 127, half = t >> 7;
    #pragma unroll
    for (int i = 0; i < 8; i++) {
        int R = half * 8 + i;
        float s1 = 0.f, s2 = 0.f, s3 = 0.f;
        #pragma unroll
        for (int dy = 0; dy < 3; dy++)
            #pragma unroll
            for (int dx = 0; dx < 3; dx++) {
                int k = dy * 3 + dx;
                s1 += rb[R + 5 + (dy - 1)]    [5 + x + (dx - 1)]     * w1[k];
                s2 += rb[R + 5 + 3 * (dy - 1)][5 + x + 3 * (dx - 1)] * w2[k];
                s3 += rb[R + 5 + 5 * (dy - 1)][5 + x + 5 * (dx - 1)] * w3[k];
            }
        hf[(size_t)dl * LL + (y0 + R) * WW + x] = f2b(a0 * s1 + a1 * s2 + a2 * s3);
    }
}

// ---------------- K6: LDS-transpose LN: y=hf*Cs+xs*Ds; LN(d); *silu(z) -----
__global__ __launch_bounds__(256) void k_ln(const bf16* __restrict__ hf,
                                            const bf16* __restrict__ xs,
                                            const float* __restrict__ csd,
                                            const float* __restrict__ Ds,
                                            const float* __restrict__ ln_g,
                                            const float* __restrict__ ln_b,
                                            const bf16* __restrict__ z,
                                            bf16* __restrict__ yout) {
    __shared__ float vt[384][36];
    __shared__ float csh[32], mu[32], rs[32];
    __shared__ float gsh[384], bsh[384], dsh[384];
    __shared__ float sred[8][33], qred[8][33];

    int bid = blockIdx.x;
    int lb = bid >> 9;                 // LL/32 = 512 tiles per batch
    int l0 = (bid & 511) * 32;
    int t = threadIdx.x;

    if (t < 32) csh[t] = csd[(size_t)lb * LL + l0 + t];
    for (int i = t; i < 384; i += 256) {
        gsh[i] = ln_g[i]; bsh[i] = ln_b[i]; dsh[i] = Ds[i];
    }
    __syncthreads();

    #pragma unroll
    for (int p = 0; p < 6; p++) {
        int d = p * 64 + (t >> 2);
        int loff = (t & 3) * 8;
        size_t off = ((size_t)lb * D_INNER + d) * LL + l0 + loff;
        short8 h8 = *(const short8*)&hf[off];
        short8 x8 = *(const short8*)&xs[off];
        float dsv = dsh[d];
        float vv[8];
        #pragma unroll
        for (int j = 0; j < 8; j++)
            vv[j] = bits2f((unsigned short)h8[j]) * csh[loff + j]
                  + bits2f((unsigned short)x8[j]) * dsv;
        *(float4*)&vt[d][loff]     = *(float4*)&vv[0];
        *(float4*)&vt[d][loff + 4] = *(float4*)&vv[4];
    }
    __syncthreads();

    {
        int l = t & 31, ch = t >> 5;
        float s = 0.f, q = 0.f;
        #pragma unroll 8
        for (int dd = 0; dd < 48; dd++) {
            float v = vt[ch * 48 + dd][l];
            s += v; q += v * v;
        }
        sred[ch][l] = s; qred[ch][l] = q;
    }
    __syncthreads();
    if (t < 32) {
        float s = 0.f, q = 0.f;
        #pragma unroll
        for (int c = 0; c < 8; c++) { s += sred[c][t]; q += qred[c][t]; }
        float m = s * (1.f / D_INNER);
        float var = q * (1.f / D_INNER) - m * m;
        mu[t] = m; rs[t] = rsqrtf(var + 1e-5f);
    }
    __syncthreads();

    {
        int l = t & 31, ch = t >> 5;
        int d0 = ch * 48;
        size_t row = ((size_t)lb * LL + l0 + l) * D_INNER + d0;
        const short8* zp = (const short8*)&z[row];
        short8* yp = (short8*)&yout[row];
        float m = mu[l], r = rs[l];
        #pragma unroll
        for (int c = 0; c < 6; c++) {
            short8 z8 = zp[c];
            unsigned short ub[8];
            #pragma unroll
            for (int j = 0; j < 8; j++) {
                int d = d0 + c * 8 + j;
                float v = vt[d][l];
                float yn = (v - m) * r * gsh[d] + bsh[d];
                float zv = bits2f((unsigned short)z8[j]);
                float sz = zv * fsig(zv);
                ub[j] = fbits(yn * sz);
            }
            yp[c] = *(short8*)ub;
        }
    }
}

// ---------------- K7: out = Y @ Woutb^T (MFMA, f32 output) -----------------
__global__ __launch_bounds__(256) void k_gemm_out(const bf16* __restrict__ Y,
                                                  const unsigned short* __restrict__ Wb,
                                                  float* __restrict__ out,
                                                  int b_off) {
    __shared__ short Al[128][40];
    __shared__ short Bl[64][40];
    int t = threadIdx.x, lane = t & 63, w = t >> 6;
    int wr = w >> 1, wc = w & 1;
    int n0 = blockIdx.x * 64, m0 = blockIdx.y * 128;
    f32x4 acc[4][2];
    f32x4 zv = {0.f, 0.f, 0.f, 0.f};
    #pragma unroll
    for (int i = 0; i < 4; i++) { acc[i][0] = zv; acc[i][1] = zv; }

    int sr = t >> 1, sc = (t & 1) * 16;
    const unsigned short* Ab = (const unsigned short*)Y + (size_t)(m0 + sr) * D_INNER + sc;
    int br = t >> 2, bc = (t & 3) * 8;
    const unsigned short* Bb = Wb + (size_t)(n0 + br) * D_INNER + bc;

    for (int k0 = 0; k0 < D_INNER; k0 += 32) {
        int4 av0 = *(const int4*)(Ab + k0);
        int4 av1 = *(const int4*)(Ab + k0 + 8);
        int4 bv0 = *(const int4*)(Bb + k0);
        __syncthreads();
        *(int4*)&Al[sr][sc]     = av0;
        *(int4*)&Al[sr][sc + 8] = av1;
        *(int4*)&Bl[br][bc]     = bv0;
        __syncthreads();
        short8 af[4], bfr[2];
        #pragma unroll
        for (int f = 0; f < 4; f++)
            af[f] = *(const short8*)&Al[wr * 64 + f * 16 + (lane & 15)][(lane >> 4) * 8];
        #pragma unroll
        for (int f = 0; f < 2; f++)
            bfr[f] = *(const short8*)&Bl[wc * 32 + f * 16 + (lane & 15)][(lane >> 4) * 8];
        #pragma unroll
        for (int i = 0; i < 4; i++)
            #pragma unroll
            for (int j = 0; j < 2; j++)
                acc[i][j] = __builtin_amdgcn_mfma_f32_16x16x32_bf16(af[i], bfr[j], acc[i][j], 0, 0, 0);
    }

    size_t gm = (size_t)b_off * LL + m0;
    #pragma unroll
    for (int i = 0; i < 4; i++) {
        int mB = wr * 64 + i * 16 + ((lane >> 4) << 2);
        #pragma unroll
        for (int j = 0; j < 2; j++) {
            int n = n0 + wc * 32 + j * 16 + (lane & 15);
            f32x4 v = acc[i][j];
            #pragma unroll
            for (int r = 0; r < 4; r++)
                out[(gm + mB + r) * D_MODEL + n] = v[r];
        }
    }
}

extern "C" void kernel_launch(void* const* d_in, const int* in_sizes, int n_in,
                              void* d_out, int out_size, void* d_ws, size_t ws_size,
                              hipStream_t stream) {
    const float* x        = (const float*)d_in[0];
    const float* Win      = (const float*)d_in[1];
    const float* conv_w   = (const float*)d_in[2];
    const float* conv_b   = (const float*)d_in[3];
    const float* x_proj_w = (const float*)d_in[4];
    const float* dt_w     = (const float*)d_in[5];
    const float* dt_b     = (const float*)d_in[6];
    const float* A_logs   = (const float*)d_in[7];
    const float* Ds       = (const float*)d_in[8];
    const float* k3w      = (const float*)d_in[9];
    const float* k3_1w    = (const float*)d_in[10];
    const float* k3_2w    = (const float*)d_in[11];
    const float* alpha    = (const float*)d_in[12];
    const float* ln_g     = (const float*)d_in[13];
    const float* ln_b     = (const float*)d_in[14];
    const float* Wout     = (const float*)d_in[15];

    // fixed head: bf16 copies of Win, Wout, padded dt_w
    unsigned short* Winb  = (unsigned short*)d_ws;
    unsigned short* Woutb = Winb + 2 * D_INNER * D_MODEL;      // 147456
    unsigned short* wpb   = Woutb + D_MODEL * D_INNER;         // +73728
    char* pbase = (char*)(wpb + D_INNER * 32);                 // +12288

    const size_t head = (size_t)(2 * D_INNER * D_MODEL + D_MODEL * D_INNER + D_INNER * 32) * 2;
    const size_t per_batch = (size_t)4 * D_INNER * LL * 2   // b0..b3 bf16
                           + (size_t)2 * LL * 4              // bsd + csd f32
                           + (size_t)LL * 32 * 2             // dtsb bf16
                           + (size_t)LL * D_MODEL * 2;       // Xb bf16
    int nb = (int)((ws_size - head) / per_batch);
    if (nb > BATCH) nb = BATCH;
    if (nb < 1) nb = 1;

    size_t Sb = (size_t)nb * D_INNER * LL;
    bf16* b0 = (bf16*)pbase;         // xi -> delta -> hf
    bf16* b1 = b0 + Sb;              // xs
    bf16* b2 = b1 + Sb;              // z (NHWC)
    bf16* b3 = b2 + Sb;              // h -> gated y (NHWC)
    float* bsd = (float*)(b3 + Sb);            // nb*LL
    float* csd = bsd + (size_t)nb * LL;        // nb*LL
    unsigned short* dtsb = (unsigned short*)(csd + (size_t)nb * LL);  // nb*LL*32
    unsigned short* Xb = dtsb + (size_t)nb * LL * 32;

    k_cvt <<<(2 * D_INNER * D_MODEL) / 2048, 256, 0, stream>>>(Win, Winb);
    k_cvt <<<(D_MODEL * D_INNER) / 2048, 256, 0, stream>>>(Wout, Woutb);
    k_padw<<<(D_INNER * 32) / 256, 256, 0, stream>>>(dt_w, wpb);

    for (int boff = 0; boff < BATCH; boff += nb) {
        int cur = BATCH - boff < nb ? BATCH - boff : nb;
        k_cvt     <<<(cur * LL * D_MODEL) / 2048, 256, 0, stream>>>(x + (size_t)boff * LL * D_MODEL, Xb);
        k_gemm_xz <<<dim3(6, cur * 128), 256, 0, stream>>>(Xb, Winb, b0, b2);
        k_conv_silu<<<cur * D_INNER * 8, 256, 0, stream>>>(b0, conv_w, conv_b, b1);
        k_xdbl    <<<cur * 256, 256, 0, stream>>>(b1, x_proj_w, dtsb, bsd, csd);
        k_delta   <<<dim3(24, cur * 32), 256, 0, stream>>>(wpb, dtsb, dt_b, b0);
        k_scan    <<<cur * D_INNER, 512, 0, stream>>>(b1, b0, bsd, A_logs, b3);
        k_mconv   <<<cur * D_INNER * 8, 256, 0, stream>>>(b3, k3w, k3_1w, k3_2w, alpha, b0);
        k_ln      <<<cur * 512, 256, 0, stream>>>(b0, b1, csd, Ds, ln_g, ln_b, b2, b3);
        k_gemm_out<<<dim3(3, cur * 128), 256, 0, stream>>>(b3, Woutb, (float*)d_out, boff);
    }
}

// Round 15
// 325.853 us; speedup vs baseline: 1.1810x; 1.0546x over previous
//
#include <hip/hip_runtime.h>
#include <hip/hip_bf16.h>

#define D_MODEL 192
#define D_INNER 384
#define DT_RANK 12
#define BATCH   4
#define HH      128
#define WW      128
#define LL      (HH*WW)   // 16384 = 2^14

typedef __hip_bfloat16 bf16;
typedef __attribute__((ext_vector_type(8))) short short8;
typedef __attribute__((ext_vector_type(4))) float f32x4;

__device__ __forceinline__ float b2f(bf16 v) { return __bfloat162float(v); }
__device__ __forceinline__ bf16  f2b(float v) { return __float2bfloat16(v); }
__device__ __forceinline__ unsigned short fbits(float v) {
    union { bf16 h; unsigned short u; } c; c.h = __float2bfloat16(v); return c.u;
}
__device__ __forceinline__ float bits2f(unsigned short u) {
    union { unsigned u32; float f; } c; c.u32 = (unsigned)u << 16; return c.f;
}
// hardware transcendentals (v_exp_f32 / v_log_f32 / v_rcp_f32, ~1ulp)
__device__ __forceinline__ float fsig(float x) {
    return __builtin_amdgcn_rcpf(1.f + __expf(-x));
}
__device__ __forceinline__ float fsoftplus(float s) {
    return (s > 20.f) ? s : __logf(1.f + __expf(s));
}

// ---------------- K0: f32 -> bf16 convert (n multiple of 2048) -------------
__global__ __launch_bounds__(256) void k_cvt(const float* __restrict__ src,
                                             unsigned short* __restrict__ dst) {
    size_t i = ((size_t)blockIdx.x * 256 + threadIdx.x) * 8;
    float4 f0 = *(const float4*)(src + i);
    float4 f1 = *(const float4*)(src + i + 4);
    unsigned short u[8] = {fbits(f0.x), fbits(f0.y), fbits(f0.z), fbits(f0.w),
                           fbits(f1.x), fbits(f1.y), fbits(f1.z), fbits(f1.w)};
    *(int4*)(dst + i) = *(const int4*)u;
}

// ---------------- K0b: dt_w (384x12 f32) -> padded bf16 [384][32] ----------
__global__ __launch_bounds__(256) void k_padw(const float* __restrict__ dt_w,
                                              unsigned short* __restrict__ wp) {
    int i = blockIdx.x * 256 + threadIdx.x;    // 384*32 = 12288
    int d = i >> 5, r = i & 31;
    float v = (r < 12) ? dt_w[d * 12 + r] : 0.f;
    wp[i] = fbits(v);
}

// ---------------- K1: xz = Xb @ Winb^T (MFMA) ; split xi (NCHW) / z --------
__global__ __launch_bounds__(256) void k_gemm_xz(const unsigned short* __restrict__ Xb,
                                                 const unsigned short* __restrict__ Wb,
                                                 bf16* __restrict__ xi,
                                                 bf16* __restrict__ z) {
    __shared__ short Al[128][40];
    __shared__ short Bl[128][40];
    int t = threadIdx.x, lane = t & 63, w = t >> 6;
    int wr = w >> 1, wc = w & 1;
    int n0 = blockIdx.x * 128, m0 = blockIdx.y * 128;
    f32x4 acc[4][4];
    f32x4 zv = {0.f, 0.f, 0.f, 0.f};
    #pragma unroll
    for (int i = 0; i < 4; i++)
        #pragma unroll
        for (int j = 0; j < 4; j++) acc[i][j] = zv;

    int sr = t >> 1, sc = (t & 1) * 16;
    const unsigned short* Ab = Xb + (size_t)(m0 + sr) * D_MODEL + sc;
    const unsigned short* Bb = Wb + (size_t)(n0 + sr) * D_MODEL + sc;

    for (int k0 = 0; k0 < D_MODEL; k0 += 32) {
        int4 av0 = *(const int4*)(Ab + k0);
        int4 av1 = *(const int4*)(Ab + k0 + 8);
        int4 bv0 = *(const int4*)(Bb + k0);
        int4 bv1 = *(const int4*)(Bb + k0 + 8);
        __syncthreads();
        *(int4*)&Al[sr][sc]     = av0;
        *(int4*)&Al[sr][sc + 8] = av1;
        *(int4*)&Bl[sr][sc]     = bv0;
        *(int4*)&Bl[sr][sc + 8] = bv1;
        __syncthreads();
        short8 af[4], bfr[4];
        #pragma unroll
        for (int f = 0; f < 4; f++) {
            af[f]  = *(const short8*)&Al[wr * 64 + f * 16 + (lane & 15)][(lane >> 4) * 8];
            bfr[f] = *(const short8*)&Bl[wc * 64 + f * 16 + (lane & 15)][(lane >> 4) * 8];
        }
        #pragma unroll
        for (int i = 0; i < 4; i++)
            #pragma unroll
            for (int j = 0; j < 4; j++)
                acc[i][j] = __builtin_amdgcn_mfma_f32_16x16x32_bf16(af[i], bfr[j], acc[i][j], 0, 0, 0);
    }

    #pragma unroll
    for (int i = 0; i < 4; i++) {
        int mB = m0 + wr * 64 + i * 16 + ((lane >> 4) << 2);
        int lb = mB >> 14, l = mB & (LL - 1);
        #pragma unroll
        for (int j = 0; j < 4; j++) {
            int n = n0 + wc * 64 + j * 16 + (lane & 15);
            f32x4 v = acc[i][j];
            if (n < D_INNER) {
                union { short4 s4; unsigned short u[4]; } p;
                #pragma unroll
                for (int r = 0; r < 4; r++) p.u[r] = fbits(v[r]);
                *(short4*)&xi[((size_t)lb * D_INNER + n) * LL + l] = p.s4;
            } else {
                #pragma unroll
                for (int r = 0; r < 4; r++)
                    z[(size_t)(mB + r) * D_INNER + (n - D_INNER)] = f2b(v[r]);
            }
        }
    }
}

// ---------------- K2: depthwise 3x3 conv (zero pad) + bias + SiLU ----------
// row-register blocking: 30 LDS reads per 8 outputs (was 72)
__global__ __launch_bounds__(256) void k_conv_silu(const bf16* __restrict__ xi,
                                                   const float* __restrict__ w,
                                                   const float* __restrict__ bias,
                                                   bf16* __restrict__ xs) {
    __shared__ float rb[18][144];      // data cols 8..135, halo 7 / 136 (zero)
    int bid = blockIdx.x;
    int dl = bid >> 3;              // chunk-local (lb*384+d)
    int d  = dl % D_INNER;
    int y0 = (bid & 7) * 16;
    int t  = threadIdx.x;
    const bf16* src = xi + (size_t)dl * LL;

    for (int rr = (t >> 4); rr < 18; rr += 16) {
        int c  = t & 15;
        int yy = y0 + rr - 1;
        float vals[8];
        if (yy >= 0 && yy < HH) {
            short8 s8 = *(const short8*)&src[yy * WW + c * 8];
            #pragma unroll
            for (int j = 0; j < 8; j++) vals[j] = bits2f((unsigned short)s8[j]);
        } else {
            #pragma unroll
            for (int j = 0; j < 8; j++) vals[j] = 0.f;
        }
        *(float4*)&rb[rr][8 + c * 8]     = *(float4*)&vals[0];
        *(float4*)&rb[rr][8 + c * 8 + 4] = *(float4*)&vals[4];
        if (c == 0)  rb[rr][7]   = 0.f;
        if (c == 15) rb[rr][136] = 0.f;
    }
    float wk[9];
    #pragma unroll
    for (int k = 0; k < 9; k++) wk[k] = w[d * 9 + k];
    float bs = bias[d];
    __syncthreads();

    int x = t & 127, half = t >> 7;
    int Rb = half * 8;
    float out[8];
    #pragma unroll
    for (int i = 0; i < 8; i++) out[i] = bs;
    #pragma unroll
    for (int dx = 0; dx < 3; dx++) {
        float v[10];
        #pragma unroll
        for (int k = 0; k < 10; k++) v[k] = rb[Rb + k][7 + x + dx];
        #pragma unroll
        for (int i = 0; i < 8; i++)
            out[i] += v[i] * wk[dx] + v[i + 1] * wk[3 + dx] + v[i + 2] * wk[6 + dx];
    }
    #pragma unroll
    for (int i = 0; i < 8; i++) {
        float s = out[i] * fsig(out[i]);
        xs[(size_t)dl * LL + (y0 + Rb + i) * WW + x] = f2b(s);
    }
}

// ---------------- K3: x_dbl: 64l x 4dg blocks, LDS-reduced -----------------
__global__ __launch_bounds__(256) void k_xdbl(const bf16* __restrict__ xs,
                                              const float* __restrict__ xpw,
                                              unsigned short* __restrict__ dtsb,
                                              float* __restrict__ bsd,
                                              float* __restrict__ csd) {
    __shared__ float part[4][64][17];
    int bid = blockIdx.x;
    int lb  = bid >> 8;              // 256 tiles per batch
    int l0  = (bid & 255) * 64;
    int t = threadIdx.x;
    int l = t & 63, dg = t >> 6;

    const bf16* base = xs + (size_t)lb * D_INNER * LL + l0 + l;
    float acc[14] = {};
    for (int d0 = dg * 96; d0 < dg * 96 + 96; d0 += 8) {
        float v[8];
        #pragma unroll
        for (int q = 0; q < 8; q++) v[q] = b2f(base[(size_t)(d0 + q) * LL]);
        #pragma unroll
        for (int q = 0; q < 8; q++) {
            #pragma unroll
            for (int k = 0; k < 14; k++) acc[k] += xpw[k * D_INNER + d0 + q] * v[q];
        }
    }
    #pragma unroll
    for (int k = 0; k < 14; k++) part[dg][l][k] = acc[k];
    __syncthreads();

    if (t < 64) {
        float s[14];
        #pragma unroll
        for (int k = 0; k < 14; k++)
            s[k] = part[0][t][k] + part[1][t][k] + part[2][t][k] + part[3][t][k];
        unsigned short pk[32];
        #pragma unroll
        for (int k = 0; k < 12; k++) pk[k] = fbits(s[k]);
        #pragma unroll
        for (int k = 12; k < 32; k++) pk[k] = 0;
        int4* dst = (int4*)&dtsb[((size_t)lb * LL + l0 + t) << 5];
        #pragma unroll
        for (int q = 0; q < 4; q++) dst[q] = ((const int4*)pk)[q];
        bsd[(size_t)lb * LL + l0 + t] = s[12];
        csd[(size_t)lb * LL + l0 + t] = s[13];
    }
}

// ---------------- K3b: delta = softplus(dt_w @ dts + dt_b)  (MFMA) ---------
__global__ __launch_bounds__(256) void k_delta(const unsigned short* __restrict__ wp,
                                               const unsigned short* __restrict__ dtsb,
                                               const float* __restrict__ dt_b,
                                               bf16* __restrict__ delta) {
    __shared__ float bsm[16];
    int m0 = blockIdx.x * 16;
    int nbk = blockIdx.y;
    int lb = nbk >> 5;                 // 32 n-tiles (512 wide) per batch
    int n0 = (nbk & 31) * 512;
    int t = threadIdx.x, lane = t & 63, w = t >> 6;
    if (t < 16) bsm[t] = dt_b[m0 + t];
    short8 af = *(const short8*)&wp[(m0 + (lane & 15)) * 32 + (lane >> 4) * 8];
    __syncthreads();
    f32x4 zv = {0.f, 0.f, 0.f, 0.f};
    int row = (lane >> 4) * 4;
    #pragma unroll
    for (int s = 0; s < 8; s++) {
        int n = n0 + w * 128 + s * 16 + (lane & 15);
        short8 bf8 = *(const short8*)&dtsb[(((size_t)lb * LL + n) << 5) + (lane >> 4) * 8];
        f32x4 c = __builtin_amdgcn_mfma_f32_16x16x32_bf16(af, bf8, zv, 0, 0, 0);
        #pragma unroll
        for (int r = 0; r < 4; r++) {
            float sv = c[r] + bsm[row + r];
            float dl = fsoftplus(sv);
            delta[((size_t)lb * D_INNER + m0 + row + r) * LL + n] = f2b(dl);
        }
    }
}

// ---------------- K4: block-parallel scan, one 512-thread block per seq ----
__global__ __launch_bounds__(512, 4) void k_scan(const bf16* __restrict__ xs,
                                                 const bf16* __restrict__ delta,
                                                 const float* __restrict__ bsd,
                                                 const float* __restrict__ A_logs,
                                                 bf16* __restrict__ h) {
    int seq = blockIdx.x;
    int d   = seq % D_INNER;
    int lb  = seq / D_INNER;
    int t    = threadIdx.x;
    int lane = t & 63;
    int wid  = t >> 6;

    float Aval = -__expf(A_logs[d]);

    int l0 = t * 32;
    const bf16* xv = xs + (size_t)seq * LL + l0;
    const bf16* dv = delta + (size_t)seq * LL + l0;
    const float* bsp = bsd + (size_t)lb * LL + l0;

    float xsv[32], dlv[32];
    {
        int4 raw[4], rawd[4];
        const int4* src = (const int4*)xv;
        const int4* srcd = (const int4*)dv;
        #pragma unroll
        for (int q = 0; q < 4; q++) { raw[q] = src[q]; rawd[q] = srcd[q]; }
        const unsigned short* u = (const unsigned short*)raw;
        const unsigned short* ud = (const unsigned short*)rawd;
        #pragma unroll
        for (int j = 0; j < 32; j++) { xsv[j] = bits2f(u[j]); dlv[j] = bits2f(ud[j]); }
    }

    float a[32], bb[32];
    float Ar = 1.f, Br = 0.f;
    #pragma unroll
    for (int j = 0; j < 32; j++) {
        float Bsv = bsp[j];
        float dl = dlv[j];
        float av = __expf(dl * Aval);
        float bv = dl * Bsv * xsv[j];
        a[j] = av; bb[j] = bv;
        Br = av * Br + bv;
        Ar *= av;
    }

    #pragma unroll
    for (int off = 1; off < 64; off <<= 1) {
        float Ap = __shfl_up(Ar, off);
        float Bp = __shfl_up(Br, off);
        if (lane >= off) { Br = Ar * Bp + Br; Ar *= Ap; }
    }

    __shared__ float LA[8], LB[8];
    if (lane == 63) { LA[wid] = Ar; LB[wid] = Br; }
    __syncthreads();
    float Bwp = 0.f;
    for (int ww = 0; ww < wid; ww++) { Bwp = LA[ww] * Bwp + LB[ww]; }

    float Ae = __shfl_up(Ar, 1), Be = __shfl_up(Br, 1);
    if (lane == 0) { Ae = 1.f; Be = 0.f; }
    float hcur = Ae * Bwp + Be;

    unsigned pk[16];
    unsigned lo = 0;
    #pragma unroll
    for (int j = 0; j < 32; j++) {
        hcur = a[j] * hcur + bb[j];
        unsigned bits = fbits(hcur);
        if (j & 1) pk[j >> 1] = lo | (bits << 16);
        else       lo = bits;
    }
    int4* dst = (int4*)(h + (size_t)seq * LL + l0);
    #pragma unroll
    for (int q = 0; q < 4; q++) dst[q] = ((int4*)pk)[q];
}

// ---------------- K5: 3 dilated replicate-pad depthwise convs + combine ----
// row-register blocking: 126 LDS reads per 8 outputs (was 216); alpha fused
__global__ __launch_bounds__(256) void k_mconv(const bf16* __restrict__ h,
                                               const float* __restrict__ k1w,
                                               const float* __restrict__ k2w,
                                               const float* __restrict__ k3w,
                                               const float* __restrict__ alpha,
                                               bf16* __restrict__ hf) {
    __shared__ float rb[26][144];      // data cols 8..135, halo 3..7 / 136..140
    int bid = blockIdx.x;
    int dl = bid >> 3;
    int d  = dl % D_INNER;
    int y0 = (bid & 7) * 16;
    int t  = threadIdx.x;
    const bf16* src = h + (size_t)dl * LL;

    for (int rr = (t >> 4); rr < 26; rr += 16) {
        int c  = t & 15;
        int yy = min(max(y0 + rr - 5, 0), HH - 1);
        short8 s8 = *(const short8*)&src[yy * WW + c * 8];
        float vals[8];
        #pragma unroll
        for (int j = 0; j < 8; j++) vals[j] = bits2f((unsigned short)s8[j]);
        *(float4*)&rb[rr][8 + c * 8]     = *(float4*)&vals[0];
        *(float4*)&rb[rr][8 + c * 8 + 4] = *(float4*)&vals[4];
        if (c == 0) {
            #pragma unroll
            for (int q = 3; q < 8; q++) rb[rr][q] = vals[0];
        }
        if (c == 15) {
            #pragma unroll
            for (int q = 0; q < 5; q++) rb[rr][136 + q] = vals[7];
        }
    }
    float a0 = alpha[0], a1 = alpha[1], a2 = alpha[2];
    float w1[9], w2[9], w3[9];
    #pragma unroll
    for (int k = 0; k < 9; k++) {
        w1[k] = a0 * k1w[d * 9 + k];
        w2[k] = a1 * k2w[d * 9 + k];
        w3[k] = a2 * k3w[d * 9 + k];
    }
    __syncthreads();

    int x = t & 127, half = t >> 7;
    int Rb = half * 8;
    float out[8] = {};
    // dil 1: LDS rows Rb+4 .. Rb+13
    #pragma unroll
    for (int dx = 0; dx < 3; dx++) {
        float v[10];
        #pragma unroll
        for (int k = 0; k < 10; k++) v[k] = rb[Rb + 4 + k][7 + x + dx];
        #pragma unroll
        for (int i = 0; i < 8; i++)
            out[i] += v[i] * w1[dx] + v[i + 1] * w1[3 + dx] + v[i + 2] * w1[6 + dx];
    }
    // dil 3: LDS rows Rb+2 .. Rb+15
    #pragma unroll
    for (int dx = 0; dx < 3; dx++) {
        float v[14];
        #pragma unroll
        for (int k = 0; k < 14; k++) v[k] = rb[Rb + 2 + k][8 + x + 3 * (dx - 1)];
        #pragma unroll
        for (int i = 0; i < 8; i++)
            out[i] += v[i] * w2[dx] + v[i + 3] * w2[3 + dx] + v[i + 6] * w2[6 + dx];
    }
    // dil 5: LDS rows Rb .. Rb+17
    #pragma unroll
    for (int dx = 0; dx < 3; dx++) {
        float v[18];
        #pragma unroll
        for (int k = 0; k < 18; k++) v[k] = rb[Rb + k][8 + x + 5 * (dx - 1)];
        #pragma unroll
        for (int i = 0; i < 8; i++)
            out[i] += v[i] * w3[dx] + v[i + 5] * w3[3 + dx] + v[i + 10] * w3[6 + dx];
    }
    #pragma unroll
    for (int i = 0; i < 8; i++)
        hf[(size_t)dl * LL + (y0 + Rb + i) * WW + x] = f2b(out[i]);
}

// ---------------- K6: LDS-transpose LN: y=hf*Cs+xs*Ds; LN(d); *silu(z) -----
__global__ __launch_bounds__(256) void k_ln(const bf16* __restrict__ hf,
                                            const bf16* __restrict__ xs,
                                            const float* __restrict__ csd,
                                            const float* __restrict__ Ds,
                                            const float* __restrict__ ln_g,
                                            const float* __restrict__ ln_b,
                                            const bf16* __restrict__ z,
                                            bf16* __restrict__ yout) {
    __shared__ float vt[384][36];
    __shared__ float csh[32], mu[32], rs[32];
    __shared__ float gsh[384], bsh[384], dsh[384];
    __shared__ float sred[8][33], qred[8][33];

    int bid = blockIdx.x;
    int lb = bid >> 9;                 // LL/32 = 512 tiles per batch
    int l0 = (bid & 511) * 32;
    int t = threadIdx.x;

    if (t < 32) csh[t] = csd[(size_t)lb * LL + l0 + t];
    for (int i = t; i < 384; i += 256) {
        gsh[i] = ln_g[i]; bsh[i] = ln_b[i]; dsh[i] = Ds[i];
    }
    __syncthreads();

    #pragma unroll
    for (int p = 0; p < 6; p++) {
        int d = p * 64 + (t >> 2);
        int loff = (t & 3) * 8;
        size_t off = ((size_t)lb * D_INNER + d) * LL + l0 + loff;
        short8 h8 = *(const short8*)&hf[off];
        short8 x8 = *(const short8*)&xs[off];
        float dsv = dsh[d];
        float vv[8];
        #pragma unroll
        for (int j = 0; j < 8; j++)
            vv[j] = bits2f((unsigned short)h8[j]) * csh[loff + j]
                  + bits2f((unsigned short)x8[j]) * dsv;
        *(float4*)&vt[d][loff]     = *(float4*)&vv[0];
        *(float4*)&vt[d][loff + 4] = *(float4*)&vv[4];
    }
    __syncthreads();

    {
        int l = t & 31, ch = t >> 5;
        float s = 0.f, q = 0.f;
        #pragma unroll 8
        for (int dd = 0; dd < 48; dd++) {
            float v = vt[ch * 48 + dd][l];
            s += v; q += v * v;
        }
        sred[ch][l] = s; qred[ch][l] = q;
    }
    __syncthreads();
    if (t < 32) {
        float s = 0.f, q = 0.f;
        #pragma unroll
        for (int c = 0; c < 8; c++) { s += sred[c][t]; q += qred[c][t]; }
        float m = s * (1.f / D_INNER);
        float var = q * (1.f / D_INNER) - m * m;
        mu[t] = m; rs[t] = rsqrtf(var + 1e-5f);
    }
    __syncthreads();

    {
        int l = t & 31, ch = t >> 5;
        int d0 = ch * 48;
        size_t row = ((size_t)lb * LL + l0 + l) * D_INNER + d0;
        const short8* zp = (const short8*)&z[row];
        short8* yp = (short8*)&yout[row];
        float m = mu[l], r = rs[l];
        #pragma unroll
        for (int c = 0; c < 6; c++) {
            short8 z8 = zp[c];
            unsigned short ub[8];
            #pragma unroll
            for (int j = 0; j < 8; j++) {
                int d = d0 + c * 8 + j;
                float v = vt[d][l];
                float yn = (v - m) * r * gsh[d] + bsh[d];
                float zv = bits2f((unsigned short)z8[j]);
                float sz = zv * fsig(zv);
                ub[j] = fbits(yn * sz);
            }
            yp[c] = *(short8*)ub;
        }
    }
}

// ---------------- K7: out = Y @ Woutb^T (MFMA, f32 output) -----------------
__global__ __launch_bounds__(256) void k_gemm_out(const bf16* __restrict__ Y,
                                                  const unsigned short* __restrict__ Wb,
                                                  float* __restrict__ out,
                                                  int b_off) {
    __shared__ short Al[128][40];
    __shared__ short Bl[64][40];
    int t = threadIdx.x, lane = t & 63, w = t >> 6;
    int wr = w >> 1, wc = w & 1;
    int n0 = blockIdx.x * 64, m0 = blockIdx.y * 128;
    f32x4 acc[4][2];
    f32x4 zv = {0.f, 0.f, 0.f, 0.f};
    #pragma unroll
    for (int i = 0; i < 4; i++) { acc[i][0] = zv; acc[i][1] = zv; }

    int sr = t >> 1, sc = (t & 1) * 16;
    const unsigned short* Ab = (const unsigned short*)Y + (size_t)(m0 + sr) * D_INNER + sc;
    int br = t >> 2, bc = (t & 3) * 8;
    const unsigned short* Bb = Wb + (size_t)(n0 + br) * D_INNER + bc;

    for (int k0 = 0; k0 < D_INNER; k0 += 32) {
        int4 av0 = *(const int4*)(Ab + k0);
        int4 av1 = *(const int4*)(Ab + k0 + 8);
        int4 bv0 = *(const int4*)(Bb + k0);
        __syncthreads();
        *(int4*)&Al[sr][sc]     = av0;
        *(int4*)&Al[sr][sc + 8] = av1;
        *(int4*)&Bl[br][bc]     = bv0;
        __syncthreads();
        short8 af[4], bfr[2];
        #pragma unroll
        for (int f = 0; f < 4; f++)
            af[f] = *(const short8*)&Al[wr * 64 + f * 16 + (lane & 15)][(lane >> 4) * 8];
        #pragma unroll
        for (int f = 0; f < 2; f++)
            bfr[f] = *(const short8*)&Bl[wc * 32 + f * 16 + (lane & 15)][(lane >> 4) * 8];
        #pragma unroll
        for (int i = 0; i < 4; i++)
            #pragma unroll
            for (int j = 0; j < 2; j++)
                acc[i][j] = __builtin_amdgcn_mfma_f32_16x16x32_bf16(af[i], bfr[j], acc[i][j], 0, 0, 0);
    }

    size_t gm = (size_t)b_off * LL + m0;
    #pragma unroll
    for (int i = 0; i < 4; i++) {
        int mB = wr * 64 + i * 16 + ((lane >> 4) << 2);
        #pragma unroll
        for (int j = 0; j < 2; j++) {
            int n = n0 + wc * 32 + j * 16 + (lane & 15);
            f32x4 v = acc[i][j];
            #pragma unroll
            for (int r = 0; r < 4; r++)
                out[(gm + mB + r) * D_MODEL + n] = v[r];
        }
    }
}

extern "C" void kernel_launch(void* const* d_in, const int* in_sizes, int n_in,
                              void* d_out, int out_size, void* d_ws, size_t ws_size,
                              hipStream_t stream) {
    const float* x        = (const float*)d_in[0];
    const float* Win      = (const float*)d_in[1];
    const float* conv_w   = (const float*)d_in[2];
    const float* conv_b   = (const float*)d_in[3];
    const float* x_proj_w = (const float*)d_in[4];
    const float* dt_w     = (const float*)d_in[5];
    const float* dt_b     = (const float*)d_in[6];
    const float* A_logs   = (const float*)d_in[7];
    const float* Ds       = (const float*)d_in[8];
    const float* k3w      = (const float*)d_in[9];
    const float* k3_1w    = (const float*)d_in[10];
    const float* k3_2w    = (const float*)d_in[11];
    const float* alpha    = (const float*)d_in[12];
    const float* ln_g     = (const float*)d_in[13];
    const float* ln_b     = (const float*)d_in[14];
    const float* Wout     = (const float*)d_in[15];

    // fixed head: bf16 copies of Win, Wout, padded dt_w
    unsigned short* Winb  = (unsigned short*)d_ws;
    unsigned short* Woutb = Winb + 2 * D_INNER * D_MODEL;      // 147456
    unsigned short* wpb   = Woutb + D_MODEL * D_INNER;         // +73728
    char* pbase = (char*)(wpb + D_INNER * 32);                 // +12288

    const size_t head = (size_t)(2 * D_INNER * D_MODEL + D_MODEL * D_INNER + D_INNER * 32) * 2;
    const size_t per_batch = (size_t)4 * D_INNER * LL * 2   // b0..b3 bf16
                           + (size_t)2 * LL * 4              // bsd + csd f32
                           + (size_t)LL * 32 * 2             // dtsb bf16
                           + (size_t)LL * D_MODEL * 2;       // Xb bf16
    int nb = (int)((ws_size - head) / per_batch);
    if (nb > BATCH) nb = BATCH;
    if (nb < 1) nb = 1;

    size_t Sb = (size_t)nb * D_INNER * LL;
    bf16* b0 = (bf16*)pbase;         // xi -> delta -> hf
    bf16* b1 = b0 + Sb;              // xs
    bf16* b2 = b1 + Sb;              // z (NHWC)
    bf16* b3 = b2 + Sb;              // h -> gated y (NHWC)
    float* bsd = (float*)(b3 + Sb);            // nb*LL
    float* csd = bsd + (size_t)nb * LL;        // nb*LL
    unsigned short* dtsb = (unsigned short*)(csd + (size_t)nb * LL);  // nb*LL*32
    unsigned short* Xb = dtsb + (size_t)nb * LL * 32;

    k_cvt <<<(2 * D_INNER * D_MODEL) / 2048, 256, 0, stream>>>(Win, Winb);
    k_cvt <<<(D_MODEL * D_INNER) / 2048, 256, 0, stream>>>(Wout, Woutb);
    k_padw<<<(D_INNER * 32) / 256, 256, 0, stream>>>(dt_w, wpb);

    for (int boff = 0; boff < BATCH; boff += nb) {
        int cur = BATCH - boff < nb ? BATCH - boff : nb;
        k_cvt     <<<(cur * LL * D_MODEL) / 2048, 256, 0, stream>>>(x + (size_t)boff * LL * D_MODEL, Xb);
        k_gemm_xz <<<dim3(6, cur * 128), 256, 0, stream>>>(Xb, Winb, b0, b2);
        k_conv_silu<<<cur * D_INNER * 8, 256, 0, stream>>>(b0, conv_w, conv_b, b1);
        k_xdbl    <<<cur * 256, 256, 0, stream>>>(b1, x_proj_w, dtsb, bsd, csd);
        k_delta   <<<dim3(24, cur * 32), 256, 0, stream>>>(wpb, dtsb, dt_b, b0);
        k_scan    <<<cur * D_INNER, 512, 0, stream>>>(b1, b0, bsd, A_logs, b3);
        k_mconv   <<<cur * D_INNER * 8, 256, 0, stream>>>(b3, k3w, k3_1w, k3_2w, alpha, b0);
        k_ln      <<<cur * 512, 256, 0, stream>>>(b0, b1, csd, Ds, ln_g, ln_b, b2, b3);
        k_gemm_out<<<dim3(3, cur * 128), 256, 0, stream>>>(b3, Woutb, (float*)d_out, boff);
    }
}